// Round 1
// 1628.961 us; speedup vs baseline: 1.3132x; 1.3132x over previous
//
#include <hip/hip_runtime.h>

// ScaledDotProductAttention: B=4,H=16,S=2048,D=64, fp32 in/out.
// Swapped-operand fp16 MFMA: D = mfma(K_frag, Q_frag) -> lane holds 4
// CONSECUTIVE k for one q row => int4 mask loads, float4 NT P stores.
// K read direct global->fragment (no LDS, no barriers in phase A).
// Phase B: 2 barriers/tile (Pt/Vt only), K/V reg-prefetched 1 tile ahead.
// LDS ~19KB, launch_bounds(256,4) -> 4 WG/CU (16 waves/CU).

namespace {
constexpr int Bn = 4, Hn = 16, Sn = 2048, Dn = 64;
constexpr int QB = 64;           // q-rows per workgroup
constexpr int KT = 64;           // k-rows per iteration (16 per wave)
constexpr int NIT = Sn / KT;     // 32
constexpr int NWG = (Sn / QB) * Hn * Bn;  // 2048
}

using half8   = __attribute__((ext_vector_type(8))) _Float16;
using half4   = __attribute__((ext_vector_type(4))) _Float16;
using float4v = __attribute__((ext_vector_type(4))) float;
using int4v   = __attribute__((ext_vector_type(4))) int;

__device__ __forceinline__ half8 cvt_half8(float4v a, float4v b) {
    half8 f;
    f[0] = (_Float16)a[0]; f[1] = (_Float16)a[1];
    f[2] = (_Float16)a[2]; f[3] = (_Float16)a[3];
    f[4] = (_Float16)b[0]; f[5] = (_Float16)b[1];
    f[6] = (_Float16)b[2]; f[7] = (_Float16)b[3];
    return f;
}

__global__ __launch_bounds__(256, 4) void attn_fused(
    const float* __restrict__ Qg, const float* __restrict__ Kg,
    const float* __restrict__ Vg, const int* __restrict__ Mg,
    float* __restrict__ Og, float* __restrict__ Pg)
{
    __shared__ _Float16 Vt[Dn][KT + 8];   // V^T tile: Vt[d][k]
    __shared__ _Float16 Pt[QB][KT + 8];   // P tile fp16 (producer k-slices -> full-k consumers)
    __shared__ float    lrow[QB];

    const int tid  = threadIdx.x;
    const int w    = tid >> 6;    // wave 0..3 -> k-slice w*16.. / d-slice w*16..
    const int lane = tid & 63;
    const int c15  = lane & 15;   // q (and d) index within 16
    const int q4   = lane >> 4;   // 0..3

    // XCD-chunked work remap: dispatch id L -> contiguous work chunk per XCD,
    // so each XCD's ~128 concurrent WGs span ~4 heads (K+V ~4MB ~= one L2).
    const int L    = blockIdx.x + (int)gridDim.x * (blockIdx.y + (int)gridDim.y * blockIdx.z);
    const int wid  = (L & 7) * (NWG / 8) + (L >> 3);
    const int qblk = wid & (Sn / QB - 1);
    const int h    = (wid / (Sn / QB)) & (Hn - 1);
    const int b    = wid / ((Sn / QB) * Hn);
    const int qbase = qblk * QB;

    const size_t headoff = ((size_t)(b * Hn + h)) * Sn * Dn;
    const float* Qh = Qg + headoff + (size_t)qbase * Dn;
    const float* Kh = Kg + headoff;
    const float* Vh = Vg + headoff;
    float*       Oh = Og + headoff + (size_t)qbase * Dn;
    // per-lane bases: row q = qbase + m*16 + c15, col k = t*KT + w*16 + q4*4
    const int* Mb = Mg + (size_t)(qbase + c15) * Sn + w * 16 + q4 * 4;
    float*     Pb = Pg + ((size_t)(b * Hn + h)) * Sn * Sn
                  + (size_t)(qbase + c15) * Sn + w * 16 + q4 * 4;

    if (tid < QB) lrow[tid] = 0.f;

    // ---- Q fragments direct from global (B-operand; same frag layout as A) ----
    half8 qfr[8];
    #pragma unroll
    for (int m = 0; m < 4; ++m) {
        #pragma unroll
        for (int ks = 0; ks < 2; ++ks) {
            const float* p = Qh + (size_t)(m * 16 + c15) * Dn + ks * 32 + q4 * 8;
            qfr[m * 2 + ks] = cvt_half8(*(const float4v*)p, *(const float4v*)(p + 4));
        }
    }
    __syncthreads();   // lrow init visible before phase-A atomics

    // ================= phase A: row denominators (no LDS, no barriers) =========
    const float* Kp = Kh + (size_t)(w * 16 + c15) * Dn + q4 * 8;
    float4v k0 = *(const float4v*)(Kp);
    float4v k1 = *(const float4v*)(Kp + 4);
    float4v k2 = *(const float4v*)(Kp + 32);
    float4v k3 = *(const float4v*)(Kp + 36);
    float lsum[4] = {0.f, 0.f, 0.f, 0.f};

    for (int t = 0; t < NIT; ++t) {
        const half8 a0 = cvt_half8(k0, k1);
        const half8 a1 = cvt_half8(k2, k3);
        if (t != NIT - 1) {                 // prefetch next k-slice
            Kp += KT * Dn;
            k0 = *(const float4v*)(Kp);
            k1 = *(const float4v*)(Kp + 4);
            k2 = *(const float4v*)(Kp + 32);
            k3 = *(const float4v*)(Kp + 36);
        }
        #pragma unroll
        for (int m = 0; m < 4; ++m) {
            const int4v mk = *(const int4v*)(Mb + (size_t)(m * 16) * Sn + t * KT);
            float4v D = {0.f, 0.f, 0.f, 0.f};
            D = __builtin_amdgcn_mfma_f32_16x16x32_f16(a0, qfr[2 * m + 0], D, 0, 0, 0);
            D = __builtin_amdgcn_mfma_f32_16x16x32_f16(a1, qfr[2 * m + 1], D, 0, 0, 0);
            lsum[m] += (mk[0] ? 0.f : __expf(D[0] * 0.125f))
                     + (mk[1] ? 0.f : __expf(D[1] * 0.125f))
                     + (mk[2] ? 0.f : __expf(D[2] * 0.125f))
                     + (mk[3] ? 0.f : __expf(D[3] * 0.125f));
        }
    }
    // lane holds partial sums for q = m*16+c15 over its k-slice: fold q4 groups
    #pragma unroll
    for (int m = 0; m < 4; ++m) {
        lsum[m] += __shfl_xor(lsum[m], 16);
        lsum[m] += __shfl_xor(lsum[m], 32);
    }
    if (lane < 16) {
        #pragma unroll
        for (int m = 0; m < 4; ++m) atomicAdd(&lrow[m * 16 + lane], lsum[m]);
    }
    __syncthreads();
    if (tid < QB) lrow[tid] = 1.f / lrow[tid];
    __syncthreads();
    float linv[4];
    #pragma unroll
    for (int m = 0; m < 4; ++m) linv[m] = lrow[m * 16 + c15];

    // ================= phase B: P export + PV ==================================
    float4v Of[4];
    #pragma unroll
    for (int m = 0; m < 4; ++m) Of[m] = {0.f, 0.f, 0.f, 0.f};

    Kp = Kh + (size_t)(w * 16 + c15) * Dn + q4 * 8;
    k0 = *(const float4v*)(Kp);
    k1 = *(const float4v*)(Kp + 4);
    k2 = *(const float4v*)(Kp + 32);
    k3 = *(const float4v*)(Kp + 36);

    const int vr = tid >> 4;            // 0..15: V tile row (k)
    const int vc = (tid & 15) << 2;     // 0..60: V col (d)
    const float* Vp = Vh + (size_t)vr * Dn + vc;
    float4v v0 = *(const float4v*)(Vp);
    float4v v1 = *(const float4v*)(Vp + 16 * Dn);
    float4v v2 = *(const float4v*)(Vp + 32 * Dn);
    float4v v3 = *(const float4v*)(Vp + 48 * Dn);

    #pragma unroll 1
    for (int t = 0; t < NIT; ++t) {
        const half8 a0 = cvt_half8(k0, k1);
        const half8 a1 = cvt_half8(k2, k3);
        if (t != NIT - 1) {
            Kp += KT * Dn;
            k0 = *(const float4v*)(Kp);
            k1 = *(const float4v*)(Kp + 4);
            k2 = *(const float4v*)(Kp + 32);
            k3 = *(const float4v*)(Kp + 36);
        }
        half4 ph0, ph1, ph2, ph3;
        #pragma unroll
        for (int m = 0; m < 4; ++m) {
            const int4v mk = *(const int4v*)(Mb + (size_t)(m * 16) * Sn + t * KT);
            float4v D = {0.f, 0.f, 0.f, 0.f};
            D = __builtin_amdgcn_mfma_f32_16x16x32_f16(a0, qfr[2 * m + 0], D, 0, 0, 0);
            D = __builtin_amdgcn_mfma_f32_16x16x32_f16(a1, qfr[2 * m + 1], D, 0, 0, 0);
            float4v pw;
            pw[0] = mk[0] ? 0.f : __expf(D[0] * 0.125f) * linv[m];
            pw[1] = mk[1] ? 0.f : __expf(D[1] * 0.125f) * linv[m];
            pw[2] = mk[2] ? 0.f : __expf(D[2] * 0.125f) * linv[m];
            pw[3] = mk[3] ? 0.f : __expf(D[3] * 0.125f) * linv[m];
            // write-once 1.07GB stream: bypass L2
            __builtin_nontemporal_store(pw, (float4v*)(Pb + (size_t)(m * 16) * Sn + t * KT));
            half4 hp;
            hp[0] = (_Float16)pw[0]; hp[1] = (_Float16)pw[1];
            hp[2] = (_Float16)pw[2]; hp[3] = (_Float16)pw[3];
            if (m == 0) ph0 = hp; else if (m == 1) ph1 = hp;
            else if (m == 2) ph2 = hp; else ph3 = hp;
        }
        __syncthreads();     // all waves finished PV(t-1) reads of Pt/Vt
        *(half4*)&Pt[ 0 + c15][w * 16 + q4 * 4] = ph0;
        *(half4*)&Pt[16 + c15][w * 16 + q4 * 4] = ph1;
        *(half4*)&Pt[32 + c15][w * 16 + q4 * 4] = ph2;
        *(half4*)&Pt[48 + c15][w * 16 + q4 * 4] = ph3;
        // Vt[d][k] <- V[k][d]
        Vt[vc + 0][vr +  0] = (_Float16)v0[0];
        Vt[vc + 1][vr +  0] = (_Float16)v0[1];
        Vt[vc + 2][vr +  0] = (_Float16)v0[2];
        Vt[vc + 3][vr +  0] = (_Float16)v0[3];
        Vt[vc + 0][vr + 16] = (_Float16)v1[0];
        Vt[vc + 1][vr + 16] = (_Float16)v1[1];
        Vt[vc + 2][vr + 16] = (_Float16)v1[2];
        Vt[vc + 3][vr + 16] = (_Float16)v1[3];
        Vt[vc + 0][vr + 32] = (_Float16)v2[0];
        Vt[vc + 1][vr + 32] = (_Float16)v2[1];
        Vt[vc + 2][vr + 32] = (_Float16)v2[2];
        Vt[vc + 3][vr + 32] = (_Float16)v2[3];
        Vt[vc + 0][vr + 48] = (_Float16)v3[0];
        Vt[vc + 1][vr + 48] = (_Float16)v3[1];
        Vt[vc + 2][vr + 48] = (_Float16)v3[2];
        Vt[vc + 3][vr + 48] = (_Float16)v3[3];
        if (t != NIT - 1) {  // prefetch next V tile (latency spans PV + next QK^T)
            const float* Vn = Vp + (size_t)(t + 1) * KT * Dn;
            v0 = *(const float4v*)(Vn);
            v1 = *(const float4v*)(Vn + 16 * Dn);
            v2 = *(const float4v*)(Vn + 32 * Dn);
            v3 = *(const float4v*)(Vn + 48 * Dn);
        }
        __syncthreads();     // Pt/Vt ready
        #pragma unroll
        for (int ks = 0; ks < 2; ++ks) {
            const half8 bv = *(const half8*)&Vt[w * 16 + c15][ks * 32 + q4 * 8];
            Of[0] = __builtin_amdgcn_mfma_f32_16x16x32_f16(
                        *(const half8*)&Pt[ 0 + c15][ks * 32 + q4 * 8], bv, Of[0], 0, 0, 0);
            Of[1] = __builtin_amdgcn_mfma_f32_16x16x32_f16(
                        *(const half8*)&Pt[16 + c15][ks * 32 + q4 * 8], bv, Of[1], 0, 0, 0);
            Of[2] = __builtin_amdgcn_mfma_f32_16x16x32_f16(
                        *(const half8*)&Pt[32 + c15][ks * 32 + q4 * 8], bv, Of[2], 0, 0, 0);
            Of[3] = __builtin_amdgcn_mfma_f32_16x16x32_f16(
                        *(const half8*)&Pt[48 + c15][ks * 32 + q4 * 8], bv, Of[3], 0, 0, 0);
        }
    }

    // ---- write O: Of[m][r] = O[m*16+q4*4+r][w*16+c15] ----
    #pragma unroll
    for (int m = 0; m < 4; ++m) {
        #pragma unroll
        for (int r = 0; r < 4; ++r) {
            Oh[(size_t)(m * 16 + q4 * 4 + r) * Dn + w * 16 + c15] = Of[m][r];
        }
    }
}

extern "C" void kernel_launch(void* const* d_in, const int* in_sizes, int n_in,
                              void* d_out, int out_size, void* d_ws, size_t ws_size,
                              hipStream_t stream) {
    (void)in_sizes; (void)n_in; (void)d_ws; (void)ws_size; (void)out_size;
    // setup_inputs order: key, query, value, mask
    const float* Kg = (const float*)d_in[0];
    const float* Qg = (const float*)d_in[1];
    const float* Vg = (const float*)d_in[2];
    const int*   Mg = (const int*)d_in[3];
    float* Og = (float*)d_out;                              // output  [B,H,S,D]
    float* Pg = Og + (size_t)Bn * Hn * Sn * Dn;             // attention [B,H,S,S]
    dim3 grid(Sn / QB, Hn, Bn), block(256);
    attn_fused<<<grid, block, 0, stream>>>(Qg, Kg, Vg, Mg, Og, Pg);
}